// Round 1
// baseline (1860.223 us; speedup 1.0000x reference)
//
#include <hip/hip_runtime.h>
#include <hip/hip_bf16.h>

#define H_ 12
#define D_ 64
#define S_ 2048
#define B_ 2
#define HID_ 768

typedef short bf8 __attribute__((ext_vector_type(8)));
typedef float f4 __attribute__((ext_vector_type(4)));

#define MFMA(a,b,c) __builtin_amdgcn_mfma_f32_16x16x32_bf16(a,b,c,0,0,0)

__device__ __forceinline__ unsigned short f2bf(float f){
  __hip_bfloat16 h = __float2bfloat16(f);
  return __builtin_bit_cast(unsigned short, h);
}

__device__ __forceinline__ void st4bf(unsigned short* dst, float4 v){
  unsigned int u0 = (unsigned int)f2bf(v.x) | ((unsigned int)f2bf(v.y) << 16);
  unsigned int u1 = (unsigned int)f2bf(v.z) | ((unsigned int)f2bf(v.w) << 16);
  uint2 u; u.x = u0; u.y = u1;
  *reinterpret_cast<uint2*>(dst) = u;
}

// ---------------- QKV projection: y = x @ W^T + b, routed to bf16 buffers ----
// q,k -> [B,H,S,D]; v -> transposed [B,H,D,S]
__global__ __launch_bounds__(256) void proj_kernel(
    const float* __restrict__ Xq, const float* __restrict__ Xk, const float* __restrict__ Xv,
    const float* __restrict__ Wq_, const float* __restrict__ Wk_, const float* __restrict__ Wv_,
    const float* __restrict__ bq_, const float* __restrict__ bk_, const float* __restrict__ bv_,
    unsigned short* __restrict__ qb, unsigned short* __restrict__ kb,
    unsigned short* __restrict__ vtb)
{
  const int sel = blockIdx.z;
  const float* X    = sel==0 ? Xq  : (sel==1 ? Xk  : Xv);
  const float* W    = sel==0 ? Wq_ : (sel==1 ? Wk_ : Wv_);
  const float* bias = sel==0 ? bq_ : (sel==1 ? bk_ : bv_);
  const int m0 = blockIdx.x*64, n0 = blockIdx.y*64;
  __shared__ unsigned short lA[64*72];  // +8 pad: bank-friendly, keeps 16B align
  __shared__ unsigned short lB[64*72];
  const int tid = threadIdx.x;
  const int lane = tid & 63, w = tid >> 6;
  const int quad = lane >> 4, l16 = lane & 15;
  const int wm = (w>>1)*32, wn = (w&1)*32;
  f4 acc[2][2] = {};
  for (int k0=0; k0<HID_; k0+=64){
    #pragma unroll
    for (int i=0;i<4;i++){
      int idx = tid + i*256;               // 0..1023
      int r = idx>>4, c4 = idx&15;         // 64 rows x 16 float4
      float4 va = *reinterpret_cast<const float4*>(&X[(size_t)(m0+r)*HID_ + k0 + c4*4]);
      st4bf(&lA[r*72 + c4*4], va);
      float4 vb = *reinterpret_cast<const float4*>(&W[(size_t)(n0+r)*HID_ + k0 + c4*4]);
      st4bf(&lB[r*72 + c4*4], vb);
    }
    __syncthreads();
    #pragma unroll
    for (int kc=0;kc<2;kc++){
      bf8 a0 = *reinterpret_cast<const bf8*>(&lA[(wm    + l16)*72 + kc*32 + quad*8]);
      bf8 a1 = *reinterpret_cast<const bf8*>(&lA[(wm+16 + l16)*72 + kc*32 + quad*8]);
      bf8 b0 = *reinterpret_cast<const bf8*>(&lB[(wn    + l16)*72 + kc*32 + quad*8]);
      bf8 b1 = *reinterpret_cast<const bf8*>(&lB[(wn+16 + l16)*72 + kc*32 + quad*8]);
      acc[0][0] = MFMA(a0,b0,acc[0][0]);
      acc[0][1] = MFMA(a0,b1,acc[0][1]);
      acc[1][0] = MFMA(a1,b0,acc[1][0]);
      acc[1][1] = MFMA(a1,b1,acc[1][1]);
    }
    __syncthreads();
  }
  #pragma unroll
  for (int i=0;i<2;i++)
    #pragma unroll
    for (int j=0;j<2;j++)
      #pragma unroll
      for (int reg=0;reg<4;reg++){
        int row = m0 + wm + i*16 + quad*4 + reg;     // b*S+s
        int col = n0 + wn + j*16 + l16;              // h*64+d
        float val = acc[i][j][reg] + bias[col];
        int bb = row >> 11, s = row & 2047;
        int hh = col >> 6,  d = col & 63;
        unsigned short bv16 = f2bf(val);
        if (sel==0)      qb [((size_t)(bb*H_+hh)*S_ + s)*D_ + d] = bv16;
        else if (sel==1) kb [((size_t)(bb*H_+hh)*S_ + s)*D_ + d] = bv16;
        else             vtb[((size_t)(bb*H_+hh)*D_ + d)*S_ + s] = bv16;
      }
}

// ---------------- fused attention: scores + prev_attn_out + online softmax + PV
__global__ __launch_bounds__(256) void attn_kernel(
  const unsigned short* __restrict__ qb, const unsigned short* __restrict__ kb,
  const unsigned short* __restrict__ vtb,
  const float* __restrict__ pb, const float* __restrict__ msk,
  const float* __restrict__ prev, const int* __restrict__ flagp,
  float* __restrict__ prev_out, unsigned short* __restrict__ ctxb)
{
  const int qt = blockIdx.x, hh = blockIdx.y, bb = blockIdx.z;
  const int tid = threadIdx.x, w = tid>>6, lane = tid&63;
  const int quad = lane>>4, l16 = lane&15;
  const int flag = *flagp;
  __shared__ unsigned short lK[128*72];     // K tile [128 keys][64 d], pad 72
  __shared__ unsigned short lV[64*136];     // Vt tile [64 d][128 keys], pad 136
  __shared__ unsigned short lP[4*16*136];   // P strips per wave [16][128], pad 136
  const unsigned short* Kb = kb  + (size_t)(bb*H_+hh)*S_*D_;
  const unsigned short* Vb = vtb + (size_t)(bb*H_+hh)*D_*S_;
  const unsigned short* Qb = qb  + (size_t)(bb*H_+hh)*S_*D_;
  const int q0 = qt*64;
  const int qfr = q0 + w*16 + l16;
  bf8 qf0 = *reinterpret_cast<const bf8*>(&Qb[(size_t)qfr*D_ + quad*8]);
  bf8 qf1 = *reinterpret_cast<const bf8*>(&Qb[(size_t)qfr*D_ + 32 + quad*8]);
  const float* pbB = pb   + (size_t)hh*S_*S_;
  const float* mkB = msk  + (size_t)bb*S_*S_;
  const float* pvB = prev + (size_t)(bb*H_+hh)*S_*S_;
  float*       poB = prev_out + (size_t)(bb*H_+hh)*S_*S_;
  float m_run[4], l_run[4];
  f4 O[4] = {};
  #pragma unroll
  for (int r=0;r<4;r++){ m_run[r] = -1e30f; l_run[r] = 0.f; }
  const int qrow0 = q0 + w*16 + quad*4;     // + reg

  for (int kt=0; kt<S_; kt+=128){
    __syncthreads();                        // protect LDS from previous iter reads
    #pragma unroll
    for (int i=0;i<4;i++){
      int idx = tid + i*256;
      int r = idx>>3, c8 = idx&7;           // 128 rows x 8 uint4
      *reinterpret_cast<uint4*>(&lK[r*72 + c8*8]) =
        *reinterpret_cast<const uint4*>(&Kb[(size_t)(kt+r)*D_ + c8*8]);
    }
    #pragma unroll
    for (int i=0;i<4;i++){
      int idx = tid + i*256;
      int d = idx>>4, c16 = idx&15;         // 64 rows x 16 uint4
      *reinterpret_cast<uint4*>(&lV[d*136 + c16*8]) =
        *reinterpret_cast<const uint4*>(&Vb[(size_t)d*S_ + kt + c16*8]);
    }
    __syncthreads();
    // S = Q K^T  (both operands: row-of-[*,D] with contiguous k)
    f4 sc[8];
    #pragma unroll
    for (int c=0;c<8;c++){
      bf8 k0v = *reinterpret_cast<const bf8*>(&lK[(c*16+l16)*72 + quad*8]);
      bf8 k1v = *reinterpret_cast<const bf8*>(&lK[(c*16+l16)*72 + 32 + quad*8]);
      f4 z = {};
      z = MFMA(qf0, k0v, z);
      z = MFMA(qf1, k1v, z);
      sc[c] = z;
    }
    // assemble scores, write prev_attn_out
    #pragma unroll
    for (int c=0;c<8;c++){
      int col = kt + c*16 + l16;
      #pragma unroll
      for (int reg=0;reg<4;reg++){
        int qq = qrow0 + reg;
        size_t off = (size_t)qq*S_ + col;
        float v = (sc[c][reg] + pbB[off]) * 0.125f + mkB[off];
        if (flag) v += pvB[off];
        poB[off] = v;
        sc[c][reg] = v;
      }
    }
    // online softmax (row = quad*4+reg, cols spread over 16 lanes x 8 blocks)
    float mt[4] = {-1e30f,-1e30f,-1e30f,-1e30f};
    #pragma unroll
    for (int c=0;c<8;c++)
      #pragma unroll
      for (int reg=0;reg<4;reg++) mt[reg] = fmaxf(mt[reg], sc[c][reg]);
    #pragma unroll
    for (int off=1;off<16;off<<=1)
      #pragma unroll
      for (int reg=0;reg<4;reg++) mt[reg] = fmaxf(mt[reg], __shfl_xor(mt[reg], off, 64));
    float al[4];
    #pragma unroll
    for (int reg=0;reg<4;reg++){
      float mn = fmaxf(m_run[reg], mt[reg]);
      al[reg] = __expf(m_run[reg] - mn);
      m_run[reg] = mn;
    }
    float ps[4] = {0.f,0.f,0.f,0.f};
    #pragma unroll
    for (int c=0;c<8;c++)
      #pragma unroll
      for (int reg=0;reg<4;reg++){
        float p = __expf(sc[c][reg] - m_run[reg]);
        sc[c][reg] = p;
        ps[reg] += p;
      }
    #pragma unroll
    for (int off=1;off<16;off<<=1)
      #pragma unroll
      for (int reg=0;reg<4;reg++) ps[reg] += __shfl_xor(ps[reg], off, 64);
    #pragma unroll
    for (int reg=0;reg<4;reg++) l_run[reg] = l_run[reg]*al[reg] + ps[reg];
    #pragma unroll
    for (int n=0;n<4;n++)
      #pragma unroll
      for (int reg=0;reg<4;reg++) O[n][reg] *= al[reg];
    // P -> LDS (C-layout -> A-layout round trip)
    const int pbase = w*16*136;
    #pragma unroll
    for (int c=0;c<8;c++)
      #pragma unroll
      for (int reg=0;reg<4;reg++)
        lP[pbase + (quad*4+reg)*136 + c*16 + l16] = f2bf(sc[c][reg]);
    __syncthreads();
    // O += P V  (A from lP rows, B from Vt rows, contiguous k)
    #pragma unroll
    for (int kb_=0;kb_<4;kb_++){
      bf8 pa = *reinterpret_cast<const bf8*>(&lP[pbase + l16*136 + kb_*32 + quad*8]);
      #pragma unroll
      for (int n=0;n<4;n++){
        bf8 vv = *reinterpret_cast<const bf8*>(&lV[(n*16+l16)*136 + kb_*32 + quad*8]);
        O[n] = MFMA(pa, vv, O[n]);
      }
    }
  }
  // epilogue: ctx = O / l, store bf16 [B,S,H*D]
  #pragma unroll
  for (int reg=0;reg<4;reg++){
    float rcp = 1.f / l_run[reg];
    int qq = qrow0 + reg;
    #pragma unroll
    for (int n=0;n<4;n++)
      ctxb[(size_t)(bb*S_+qq)*HID_ + hh*D_ + n*16 + l16] = f2bf(O[n][reg]*rcp);
  }
}

// ---------------- output projection: out = ctx @ Wo^T + bo (fp32 out) --------
__global__ __launch_bounds__(256) void outproj_kernel(
  const unsigned short* __restrict__ ctxb, const float* __restrict__ Wo,
  const float* __restrict__ bo, float* __restrict__ out)
{
  const int m0 = blockIdx.x*64, n0 = blockIdx.y*64;
  __shared__ unsigned short lA[64*72];
  __shared__ unsigned short lB[64*72];
  const int tid = threadIdx.x;
  const int lane = tid&63, w = tid>>6;
  const int quad = lane>>4, l16 = lane&15;
  const int wm = (w>>1)*32, wn = (w&1)*32;
  f4 acc[2][2] = {};
  for (int k0=0;k0<HID_;k0+=64){
    #pragma unroll
    for (int i=0;i<2;i++){
      int idx = tid + i*256;                // 0..511
      int r = idx>>3, c8 = idx&7;
      *reinterpret_cast<uint4*>(&lA[r*72 + c8*8]) =
        *reinterpret_cast<const uint4*>(&ctxb[(size_t)(m0+r)*HID_ + k0 + c8*8]);
    }
    #pragma unroll
    for (int i=0;i<4;i++){
      int idx = tid + i*256;
      int r = idx>>4, c4 = idx&15;
      float4 vb = *reinterpret_cast<const float4*>(&Wo[(size_t)(n0+r)*HID_ + k0 + c4*4]);
      st4bf(&lB[r*72 + c4*4], vb);
    }
    __syncthreads();
    #pragma unroll
    for (int kc=0;kc<2;kc++){
      bf8 a0 = *reinterpret_cast<const bf8*>(&lA[(wm    + l16)*72 + kc*32 + quad*8]);
      bf8 a1 = *reinterpret_cast<const bf8*>(&lA[(wm+16 + l16)*72 + kc*32 + quad*8]);
      bf8 b0 = *reinterpret_cast<const bf8*>(&lB[(wn    + l16)*72 + kc*32 + quad*8]);
      bf8 b1 = *reinterpret_cast<const bf8*>(&lB[(wn+16 + l16)*72 + kc*32 + quad*8]);
      acc[0][0] = MFMA(a0,b0,acc[0][0]);
      acc[0][1] = MFMA(a0,b1,acc[0][1]);
      acc[1][0] = MFMA(a1,b0,acc[1][0]);
      acc[1][1] = MFMA(a1,b1,acc[1][1]);
    }
    __syncthreads();
  }
  #pragma unroll
  for (int i=0;i<2;i++)
    #pragma unroll
    for (int j=0;j<2;j++)
      #pragma unroll
      for (int reg=0;reg<4;reg++){
        int row = m0 + wm + i*16 + quad*4 + reg;
        int col = n0 + wn + j*16 + l16;
        out[(size_t)row*HID_ + col] = acc[i][j][reg] + bo[col];
      }
}

extern "C" void kernel_launch(void* const* d_in, const int* in_sizes, int n_in,
                              void* d_out, int out_size, void* d_ws, size_t ws_size,
                              hipStream_t stream) {
  const float* key   = (const float*)d_in[0];
  const float* value = (const float*)d_in[1];
  const float* query = (const float*)d_in[2];
  const float* mask  = (const float*)d_in[3];
  const float* pbias = (const float*)d_in[4];
  const float* prev  = (const float*)d_in[5];
  const int*   flag  = (const int*)d_in[6];
  const float* Wq = (const float*)d_in[7];
  const float* bq = (const float*)d_in[8];
  const float* Wk = (const float*)d_in[9];
  const float* bk = (const float*)d_in[10];
  const float* Wv = (const float*)d_in[11];
  const float* bv = (const float*)d_in[12];
  const float* Wo = (const float*)d_in[13];
  const float* bo = (const float*)d_in[14];

  const size_t NQKV = (size_t)B_*H_*S_*D_;        // 3,145,728
  unsigned short* qbuf  = (unsigned short*)d_ws;
  unsigned short* kbuf  = qbuf  + NQKV;
  unsigned short* vtbuf = kbuf  + NQKV;
  unsigned short* ctxb  = vtbuf + NQKV;

  float* out = (float*)d_out;
  float* prev_out = out + (size_t)B_*S_*HID_;     // second tuple output

  proj_kernel<<<dim3(64,12,3), 256, 0, stream>>>(
      query, key, value, Wq, Wk, Wv, bq, bk, bv, qbuf, kbuf, vtbuf);
  attn_kernel<<<dim3(S_/64, H_, B_), 256, 0, stream>>>(
      qbuf, kbuf, vtbuf, pbias, mask, prev, flag, prev_out, ctxb);
  outproj_kernel<<<dim3(64,12), 256, 0, stream>>>(ctxb, Wo, bo, out);
}